// Round 3
// baseline (438.656 us; speedup 1.0000x reference)
//
#include <hip/hip_runtime.h>

#define NBINS 32
#define DIM 64
#define RANGE_MIN_F (-5.0f)
#define RANGE_MAX_F (5.0f)
#define NCELL 64
#define LUT_STRIDE 68            // (17d + g/4) % 32 spreads LUT rows across banks
#define BLOCK 512
#define GRID 768                 // persistent: 3 blocks/CU on 256 CUs
#define INV_CW 6.4f              // NCELL / (RANGE_MAX - RANGE_MIN)
#define GBIAS 32.0f              // -RANGE_MIN * INV_CW

typedef float f32x4 __attribute__((ext_vector_type(4)));   // native vector: OK for
                                                           // __builtin_nontemporal_*

// LDS budget per block (static):
//   s_recA DIM*NBINS*16 = 32768 B   {xk, 1/w, yk, h}, slot swizzled by (p + d/4) & 31
//   s_kd2  DIM*NBINS*8  = 16384 B   {kd[p], kd[p+1]} pairs, same swizzle, aligned b64
//   s_lut  DIM*68       =  4352 B
//   total 53504 B -> 3 blocks/CU (156.7 KB of 160 KB), 24 waves/CU
//
// Swizzle rationale: d = 4*(lane%16)+e  =>  d>>2 == lane%16.  Record slot
// (p + (d>>2)) & 31 makes the b128 bank-group (slot%8) uniform across the
// wave even when all lanes share the same p (8 lanes/group, conflict-free
// schedule); unswizzled it is p%8 for every lane -> ~8-way conflict.

__global__ __launch_bounds__(BLOCK, 6) void rqs_fused(
        const float* __restrict__ x,
        const float* __restrict__ bw,
        const float* __restrict__ bh,
        const float* __restrict__ ks,
        float* __restrict__ out,
        int total) {
    __shared__ float4 s_recA[DIM * NBINS];
    __shared__ float2 s_kd2[DIM * NBINS];
    __shared__ unsigned char s_lut[DIM * LUT_STRIDE];

    const int t = threadIdx.x;

    // ---- phase 1: build records (2 groups of 64 threads) ----
    if (t < DIM) {
        const int d = t;
        const int sw = d >> 2;
        float accw = 0.0f, acch = 0.0f;
        #pragma unroll
        for (int k = 0; k < NBINS; ++k) {
            float w = bw[d * NBINS + k];
            float h = bh[d * NBINS + k];
            s_recA[d * NBINS + ((k + sw) & (NBINS - 1))] =
                make_float4(RANGE_MIN_F + accw, __builtin_amdgcn_rcpf(w),
                            RANGE_MIN_F + acch, h);
            accw += w; acch += h;
        }
    } else if (t < 2 * DIM) {
        const int d = t - DIM;
        const int sw = d >> 2;
        float prev = 1.0f;                         // kd[0] = 1
        #pragma unroll
        for (int k = 0; k < NBINS; ++k) {
            float nxt = (k < NBINS - 1) ? ks[d * (NBINS - 1) + k] : 1.0f;
            s_kd2[d * NBINS + ((k + sw) & (NBINS - 1))] = make_float2(prev, nxt);
            prev = nxt;
        }
    }
    __syncthreads();

    // ---- phase 2: LUT: lut[d][g] = max{p in [0,31] : kx[p] <= cellLeft(g)} ----
    const float cellw = (RANGE_MAX_F - RANGE_MIN_F) / (float)NCELL;
    #pragma unroll
    for (int e = 0; e < (DIM * NCELL + BLOCK - 1) / BLOCK; ++e) {
        int j = t + e * BLOCK;
        if (j < DIM * NCELL) {
            int d = j >> 6, g = j & (NCELL - 1);
            int sw = d >> 2;
            float cl = RANGE_MIN_F + (float)g * cellw;
            int p = 0;
            #pragma unroll
            for (int s = 16; s >= 1; s >>= 1) {
                // max accessed p+s over the search path is 31: in-row always
                float kxs = s_recA[d * NBINS + ((p + s + sw) & (NBINS - 1))].x;
                p += (kxs <= cl) ? s : 0;
            }
            s_lut[d * LUT_STRIDE + g] = (unsigned char)p;
        }
    }
    __syncthreads();

    // ---- per-element evaluator: 1 LUT byte + dual rec read + branch-free select ----
    auto eval1 = [&](float xv, int d) -> float {
        const int sw = d >> 2;
        float gf = fmaf(xv, INV_CW, GBIAS);
        gf = fminf(fmaxf(gf, 0.0f), (float)(NCELL - 1));   // v_med3
        int g = (int)gf;
        int p = (int)s_lut[d * LUT_STRIDE + g];
        int ix1 = d * NBINS + ((p + sw) & (NBINS - 1));
        int ix2 = d * NBINS + ((p + 1 + sw) & (NBINS - 1)); // wraps when p==31; unused then
        float4 a1 = s_recA[ix1];
        float4 a2 = s_recA[ix2];
        float2 b1 = s_kd2[ix1];
        float2 b2 = s_kd2[ix2];
        float t1 = (xv - a1.x) * a1.y;     // (x - xk) / w  — spline's own t
        float t2 = (xv - a2.x) * a2.y;
        bool adv = (t1 >= 1.0f) && (p < NBINS - 1);   // x beyond this bin's right knot
        float tt0 = adv ? t2 : t1;
        float yk  = adv ? a2.z : a1.z;
        float h   = adv ? a2.w : a1.w;
        float iw  = adv ? a2.y : a1.y;
        float dk  = adv ? b2.x : b1.x;
        float dk1 = adv ? b2.y : b1.y;
        int pp = p + (adv ? 1 : 0);
        // safety fixup for pathological >1-knot-per-cell bins (~never taken)
        while (__builtin_expect((tt0 >= 1.0f) && (pp < NBINS - 1), 0)) {
            ++pp;
            int ixf = d * NBINS + ((pp + sw) & (NBINS - 1));
            float4 aa = s_recA[ixf];
            float2 bb = s_kd2[ixf];
            tt0 = (xv - aa.x) * aa.y;
            yk = aa.z; h = aa.w; iw = aa.y; dk = bb.x; dk1 = bb.y;
        }
        float sm  = h * iw;                      // bin mean slope s = h/w
        float tt  = tt0 * (1.0f - tt0);
        float num = h * fmaf(dk, tt, sm * tt0 * tt0);
        float den = fmaf(fmaf(-2.0f, sm, dk + dk1), tt, sm);
        float y   = fmaf(num, __builtin_amdgcn_rcpf(den), yk);
        // inside upper bound: tt0 <= 1 after fixup  <=>  x <= kx_last
        bool inside = (xv >= RANGE_MIN_F) && (tt0 <= 1.0f);
        return inside ? y : xv;
    };

    // ---- phase 3: float4 streaming, persistent grid-stride, prefetch 1 deep ----
    const int tid  = blockIdx.x * BLOCK + t;
    const int TOTV = GRID * BLOCK;                 // float4 stride; 4*TOTV % 64 == 0
    const int d0   = (4 * tid) & (DIM - 1);        // dim of lane's first sub-element
    const int nvec = total >> 2;
    const f32x4* X4 = (const f32x4*)x;
    f32x4* O4 = (f32x4*)out;

    int v = tid;
    if (v < nvec) {
        f32x4 cur = __builtin_nontemporal_load(&X4[v]);
        while (true) {
            int vn = v + TOTV;
            bool more = (vn < nvec);
            f32x4 nxt = cur;
            if (more) nxt = __builtin_nontemporal_load(&X4[vn]);  // in flight during compute
            // pair-wise evaluation: caps live VGPRs (~60) under the 85-reg
            // budget that __launch_bounds__(512,6) imposes, while keeping
            // 2 independent LDS chains in flight per thread
            f32x4 r;
            r[0] = eval1(cur[0], d0 + 0);
            r[1] = eval1(cur[1], d0 + 1);
            r[2] = eval1(cur[2], d0 + 2);
            r[3] = eval1(cur[3], d0 + 3);
            __builtin_nontemporal_store(r, &O4[v]);
            if (!more) break;
            cur = nxt; v = vn;
        }
    }
    // tail (total % 4 != 0 safety; zero iterations for this problem size)
    int rem = total & 3;
    if (rem && tid < rem) {
        int i = (total & ~3) + tid;
        out[i] = eval1(x[i], i & (DIM - 1));
    }
}

extern "C" void kernel_launch(void* const* d_in, const int* in_sizes, int n_in,
                              void* d_out, int out_size, void* d_ws, size_t ws_size,
                              hipStream_t stream) {
    const float* x  = (const float*)d_in[0];
    const float* bw = (const float*)d_in[1];
    const float* bh = (const float*)d_in[2];
    const float* ks = (const float*)d_in[3];
    float* out = (float*)d_out;

    rqs_fused<<<GRID, BLOCK, 0, stream>>>(x, bw, bh, ks, out, out_size);
}